// Round 16
// baseline (157.411 us; speedup 1.0000x reference)
//
#include <hip/hip_runtime.h>
#include <hip/hip_bf16.h>

// Fused causal self-attention (GQA) for MI355X/gfx950.
// Shapes: B=2, T=2048, C=1024, H=16, Hkv=4, D=64.
// Round 16: R14 base (R15 reverted). Single change in attn: K LDS buffer
// deleted (fragments direct from global, L2-resident; swizzle cancels to
// ks*32+g*8 — R12-verified), LDS 40->24 KB, 1024 unpaired heavy-first blocks
// -> 4 blocks/CU x 4 waves = 2x wave interleave. GEMMs/prep R14-verbatim.

typedef __attribute__((ext_vector_type(8))) short s16x8;   // 8 x bf16 raw
typedef __attribute__((ext_vector_type(4))) float f32x4;
typedef __attribute__((ext_vector_type(4))) unsigned short u16x4;

#define LOG2E 1.44269504088896340736f

__device__ __forceinline__ float bf2f(unsigned short u) {
  unsigned int i = ((unsigned int)u) << 16;
  return __builtin_bit_cast(float, i);
}
__device__ __forceinline__ unsigned short f2bf(float f) {
  unsigned int i = __builtin_bit_cast(unsigned int, f);
  i += 0x7fffu + ((i >> 16) & 1u);   // RNE
  return (unsigned short)(i >> 16);
}

__device__ __forceinline__ void async16(const void* g, void* l) {
  __builtin_amdgcn_global_load_lds(
      (const __attribute__((address_space(1))) void*)g,
      (__attribute__((address_space(3))) void*)l, 16, 0, 0);
}

// ---------------- prep kernels ----------------

__global__ void conv_f32_to_bf16(const float* __restrict__ in,
                                 unsigned short* __restrict__ out, int n) {
  int i = (blockIdx.x * blockDim.x + threadIdx.x) * 4;
  if (i + 3 < n) {
    float4 v = *(const float4*)(in + i);
    u16x4 o = { f2bf(v.x), f2bf(v.y), f2bf(v.z), f2bf(v.w) };
    *(u16x4*)(out + i) = o;
  }
}

// Batched: W [1024][N_z] fp32 -> Wt [N_z][1024] bf16 for 4 weights (R14).
__global__ void transpose_conv4(const float* __restrict__ W0,
                                const float* __restrict__ W1,
                                const float* __restrict__ W2,
                                const float* __restrict__ W3,
                                unsigned short* __restrict__ D0,
                                unsigned short* __restrict__ D1,
                                unsigned short* __restrict__ D2,
                                unsigned short* __restrict__ D3) {
  __shared__ float tile[32][33];
  int z = blockIdx.z;
  const float* W = (z == 0) ? W0 : (z == 1) ? W1 : (z == 2) ? W2 : W3;
  unsigned short* Wt = (z == 0) ? D0 : (z == 1) ? D1 : (z == 2) ? D2 : D3;
  int N = (z == 1 || z == 2) ? 256 : 1024;
  const int K = 1024;
  int n0 = blockIdx.x * 32, k0 = blockIdx.y * 32;
  if (n0 >= N) return;
  int tx = threadIdx.x, ty = threadIdx.y;
  for (int i = ty; i < 32; i += 8)
    tile[i][tx] = W[(size_t)(k0 + i) * N + n0 + tx];
  __syncthreads();
  for (int i = ty; i < 32; i += 8)
    Wt[(size_t)(n0 + i) * K + k0 + tx] = f2bf(tile[tx][i]);
}

// RoPE on packed QKV [4096][1536]: heads 0..15 = Q (scaled 0.125),
// heads 16..19 = K at col offset 1024. t = row % 2048.  (R14 verbatim)
__global__ void rope_qk(unsigned short* __restrict__ QKV,
                        const float* __restrict__ cosb,
                        const float* __restrict__ sinb) {
  int idx = blockIdx.x * blockDim.x + threadIdx.x;
  int d = idx & 31;
  int hh = (idx >> 5) % 20;
  int row = idx / (32 * 20);
  int t = row & 2047;
  size_t base;
  float mul;
  if (hh < 16) { base = (size_t)row * 1536 + hh * 64 + d;               mul = 0.125f; }
  else         { base = (size_t)row * 1536 + 1024 + (hh - 16) * 64 + d; mul = 1.0f;   }
  float x1 = bf2f(QKV[base]), x2 = bf2f(QKV[base + 32]);
  float c = cosb[t * 32 + d], s = sinb[t * 32 + d];
  QKV[base]      = f2bf((x1 * c + x2 * s) * mul);
  QKV[base + 32] = f2bf((-x1 * s + x2 * c) * mul);
}

// ---------------- GEMM: C[M,N] = A[M,K] * Bt[N,K]^T (R14 verbatim) ----------------
__global__ __launch_bounds__(256) void gemm_bt(
    const unsigned short* __restrict__ A, const unsigned short* __restrict__ Bt,
    void* __restrict__ Cp, int M, int N, int K, int c_f32) {
  __shared__ unsigned short As[128 * 64];   // 16 KB
  __shared__ unsigned short Bs[64 * 64];    // 8 KB
  int tid = threadIdx.x;
  int w = tid >> 6, l = tid & 63, g = l >> 4, lr = l & 15;
  int wr = w >> 1, wc = w & 1;

  // XCD-chunked remap (gridDim.x % 8 == 0 -> bijective)
  int nb = gridDim.x, bid = blockIdx.x;
  int wg = (bid & 7) * (nb >> 3) + (bid >> 3);
  int nx = N >> 6;
  int m0 = (wg / nx) * 128, n0 = (wg % nx) * 64;
  int sk = lr & 7;

  f32x4 acc[4][2] = {};

  for (int k0 = 0; k0 < K; k0 += 64) {
#pragma unroll
    for (int i = 0; i < 4; ++i) {
      int c = i * 256 + tid;
      int row = c >> 3, srcu = ((c & 7) ^ (row & 7)) * 8;
      async16(A + (size_t)(m0 + row) * K + k0 + srcu, (char*)As + c * 16);
    }
#pragma unroll
    for (int i = 0; i < 2; ++i) {
      int c = i * 256 + tid;
      int row = c >> 3, srcu = ((c & 7) ^ (row & 7)) * 8;
      async16(Bt + (size_t)(n0 + row) * K + k0 + srcu, (char*)Bs + c * 16);
    }
    __syncthreads();

    s16x8 af[2][4], bfr[2][2];
#pragma unroll
    for (int ks = 0; ks < 2; ++ks) {
#pragma unroll
      for (int m = 0; m < 4; ++m)
        af[ks][m] = *(const s16x8*)(As + (wr * 64 + m * 16 + lr) * 64 +
                                    ((ks * 4 + g) ^ sk) * 8);
#pragma unroll
      for (int n = 0; n < 2; ++n)
        bfr[ks][n] = *(const s16x8*)(Bs + (wc * 32 + n * 16 + lr) * 64 +
                                     ((ks * 4 + g) ^ sk) * 8);
    }
#pragma unroll
    for (int ks = 0; ks < 2; ++ks)
#pragma unroll
      for (int m = 0; m < 4; ++m)
#pragma unroll
        for (int n = 0; n < 2; ++n)
          acc[m][n] = __builtin_amdgcn_mfma_f32_16x16x32_bf16(
              af[ks][m], bfr[ks][n], acc[m][n], 0, 0, 0);
    __syncthreads();
  }

  // C/D layout: row = (l>>4)*4 + r, col = l&15  [HW-verified]
  if (c_f32) {
    float* C = (float*)Cp;
#pragma unroll
    for (int m = 0; m < 4; ++m)
#pragma unroll
      for (int n = 0; n < 2; ++n)
#pragma unroll
        for (int r = 0; r < 4; ++r)
          C[(size_t)(m0 + wr * 64 + m * 16 + g * 4 + r) * N +
            n0 + wc * 32 + n * 16 + lr] = acc[m][n][r];
  } else {
    unsigned short* C = (unsigned short*)Cp;
#pragma unroll
    for (int m = 0; m < 4; ++m)
#pragma unroll
      for (int n = 0; n < 2; ++n)
#pragma unroll
        for (int r = 0; r < 4; ++r)
          C[(size_t)(m0 + wr * 64 + m * 16 + g * 4 + r) * N +
            n0 + wc * 32 + n * 16 + lr] = f2bf(acc[m][n][r]);
  }
}

// ---------------- flash attention (R14 body, K-direct, 24KB LDS) ----------------
// 1024 blocks heavy-first: qt = 31-(n>>5), bh = n&31. 4 waves; wave w owns
// q rows [qt*64+16w, +16). KVBLK=64, V double-buffered in LDS; K fragments
// read DIRECT from global (L2-resident; swizzle cancels: elem ks*32+g*8).
// Lane (g,lr) holds S[q=qw+lr][kv=nf*16+g*4+r].
__global__ __launch_bounds__(256) void attn_fused(
    const unsigned short* __restrict__ QKV, unsigned short* __restrict__ Y) {
  __shared__ unsigned short Vt[2][64 * 64];   // [d][kv], swizzled (16 KB)
  __shared__ unsigned short Pb[4][16 * 64];   // per-wave P [q][kv], swizzled (8 KB)

  const int T = 2048, CS = 1536;
  int tid = threadIdx.x;
  int w = tid >> 6, l = tid & 63, g = l >> 4, lr = l & 15;
  int n = blockIdx.x;
  int qt = 31 - (n >> 5);              // heavy blocks first
  int bh = n & 31, b = bh >> 4, h = bh & 15, kvh = h >> 2;
  int sx = lr & 7;

  const unsigned short* Qp = QKV + (size_t)b * T * CS + h * 64;
  const unsigned short* Kp = QKV + (size_t)b * T * CS + 1024 + kvh * 64;
  const unsigned short* Vp = QKV + (size_t)b * T * CS + 1280 + kvh * 64;
  unsigned short* Pw = Pb[w];

  // V steady-state stage decode: c=tid -> d in {0..24}; c=256+tid -> d+32
  int kvA = tid & 63, dA = (tid >> 6) * 8, dB = dA + 32;

  int qw = qt * 64 + w * 16;
  int q_mine = qw + lr;                // this lane's q-row

  s16x8 qf[2];
#pragma unroll
  for (int ks = 0; ks < 2; ++ks)
    qf[ks] = *(const s16x8*)(Qp + (size_t)q_mine * CS + ks * 32 + g * 8);

  f32x4 o[4] = {};
  float mrun = -1e30f, lrun = 0.f;
  int ntiles = qt + 1;

  // ---- prologue: stage V tile 0 into buffer 0 ----
#pragma unroll
  for (int i = 0; i < 2; ++i) {
    int c = i * 256 + tid;
    int kv = c & 63, d0v = (c >> 6) * 8;
    s16x8 vv = *(const s16x8*)(Vp + (size_t)kv * CS + d0v);
#pragma unroll
    for (int j = 0; j < 8; ++j)
      Vt[0][(d0v + j) * 64 + (kv ^ (j * 8))] = (unsigned short)vv[j];
  }
  __syncthreads();

  int cur = 0;
  for (int it = 0; it < ntiles; ++it) {
    int kv0 = it * 64;
    bool hasnext = (it + 1 < ntiles);

    // ---- T14 stage: issue next tile's V (->regs; written after PV) ----
    s16x8 vvA, vvB;
    if (hasnext) {
      int kvn = kv0 + 64;
      vvA = *(const s16x8*)(Vp + (size_t)(kvn + kvA) * CS + dA);
      vvB = *(const s16x8*)(Vp + (size_t)(kvn + kvA) * CS + dB);
    }

    // ---- S^T = K Q^T, K fragments direct from global (L2) ----
    const unsigned short* Vc = &Vt[cur][0];
    f32x4 s[4];
    __builtin_amdgcn_s_setprio(1);
#pragma unroll
    for (int nf = 0; nf < 4; ++nf) {
      const unsigned short* krow = Kp + (size_t)(kv0 + nf * 16 + lr) * CS;
      f32x4 z = {};
#pragma unroll
      for (int ks = 0; ks < 2; ++ks) {
        s16x8 kf = *(const s16x8*)(krow + ks * 32 + g * 8);
        z = __builtin_amdgcn_mfma_f32_16x16x32_bf16(kf, qf[ks], z, 0, 0, 0);
      }
      s[nf] = z;
    }
    __builtin_amdgcn_s_setprio(0);

    if (it == ntiles - 1) {   // diagonal tile: causal mask
#pragma unroll
      for (int nf = 0; nf < 4; ++nf)
#pragma unroll
        for (int r = 0; r < 4; ++r)
          if (kv0 + nf * 16 + g * 4 + r > q_mine) s[nf][r] = -1e30f;
    }

    // ---- softmax: 16 in-lane values + 2 shuffles (R14 verbatim) ----
    float mt = s[0][0];
#pragma unroll
    for (int nf = 0; nf < 4; ++nf)
#pragma unroll
      for (int r = 0; r < 4; ++r) mt = fmaxf(mt, s[nf][r]);
    mt = fmaxf(mt, __shfl_xor(mt, 16, 64));
    mt = fmaxf(mt, __shfl_xor(mt, 32, 64));

    if (__any(mt > mrun + 8.f)) {    // wave-uniform rescale (defer-max)
      float mnew = fmaxf(mrun, mt);
      float corr = exp2f((mrun - mnew) * LOG2E);
      float psum = 0.f;
#pragma unroll
      for (int nf = 0; nf < 4; ++nf)
#pragma unroll
        for (int r = 0; r < 4; ++r) {
          float p = exp2f((s[nf][r] - mnew) * LOG2E);
          s[nf][r] = p;
          psum += p;
        }
      psum += __shfl_xor(psum, 16, 64);
      psum += __shfl_xor(psum, 32, 64);
      lrun = lrun * corr + psum;
      mrun = mnew;
#pragma unroll
      for (int r = 0; r < 4; ++r) {
        float cr = __shfl(corr, g * 4 + r, 64);
#pragma unroll
        for (int d0 = 0; d0 < 4; ++d0) o[d0][r] *= cr;
      }
    } else {                         // fast path: no rescale
      float psum = 0.f;
#pragma unroll
      for (int nf = 0; nf < 4; ++nf)
#pragma unroll
        for (int r = 0; r < 4; ++r) {
          float p = exp2f((s[nf][r] - mrun) * LOG2E);
          s[nf][r] = p;
          psum += p;
        }
      psum += __shfl_xor(psum, 16, 64);
      psum += __shfl_xor(psum, 32, 64);
      lrun += psum;
    }

    // ---- P -> LDS [q=lr][kv], packed b64 writes (R14 verbatim) ----
#pragma unroll
    for (int nf = 0; nf < 4; ++nf) {
      u16x4 pv = { f2bf(s[nf][0]), f2bf(s[nf][1]),
                   f2bf(s[nf][2]), f2bf(s[nf][3]) };
      *(u16x4*)(Pw + lr * 64 + ((nf * 16 + g * 4) ^ (sx * 8))) = pv;
    }
    asm volatile("s_waitcnt lgkmcnt(0)" ::: "memory");
    __builtin_amdgcn_sched_barrier(0);   // rule #18

    s16x8 pf[2];
#pragma unroll
    for (int ks = 0; ks < 2; ++ks)
      pf[ks] = *(const s16x8*)(Pw + lr * 64 + ((ks * 4 + g) ^ sx) * 8);
    __builtin_amdgcn_s_setprio(1);
#pragma unroll
    for (int d0 = 0; d0 < 4; ++d0)
#pragma unroll
      for (int ks = 0; ks < 2; ++ks) {
        s16x8 vf = *(const s16x8*)(Vc + (d0 * 16 + lr) * 64 +
                                   ((ks * 4 + g) ^ sx) * 8);
        o[d0] = __builtin_amdgcn_mfma_f32_16x16x32_bf16(pf[ks], vf, o[d0], 0, 0, 0);
      }
    __builtin_amdgcn_s_setprio(0);

    // ---- write staged V regs -> back buffer ----
    if (hasnext) {
#pragma unroll
      for (int j = 0; j < 8; ++j)
        Vt[cur ^ 1][(dA + j) * 64 + (kvA ^ (j * 8))] = (unsigned short)vvA[j];
#pragma unroll
      for (int j = 0; j < 8; ++j)
        Vt[cur ^ 1][(dB + j) * 64 + (kvA ^ (j * 8))] = (unsigned short)vvB[j];
    }
    __syncthreads();   // drains lgkm (V writes); swap buffers
    cur ^= 1;
  }

  // ---- epilogue: o rows are g*4+r; lrun lives at lane (*, lr=g*4+r) ----
#pragma unroll
  for (int r = 0; r < 4; ++r) {
    float lv = __shfl(lrun, g * 4 + r, 64);
    float inv = 1.f / lv;
    size_t rowoff = (size_t)(b * T + qw + g * 4 + r) * 1024 + h * 64;
#pragma unroll
    for (int d0 = 0; d0 < 4; ++d0)
      Y[rowoff + d0 * 16 + lr] = f2bf(o[d0][r] * inv);
  }
}

// ---------------- launch ----------------

extern "C" void kernel_launch(void* const* d_in, const int* in_sizes, int n_in,
                              void* d_out, int out_size, void* d_ws, size_t ws_size,
                              hipStream_t stream) {
  const float* x    = (const float*)d_in[0];
  const float* cosb = (const float*)d_in[1];
  const float* sinb = (const float*)d_in[2];
  const float* Wq   = (const float*)d_in[3];
  const float* Wk   = (const float*)d_in[4];
  const float* Wv   = (const float*)d_in[5];
  const float* Wo   = (const float*)d_in[6];
  float* out = (float*)d_out;

  // Buffer map:
  //   d_out (16 MB): QKVb [4096][1536] bf16 = 12 MB  (dead at final gemm)
  //   d_ws: xb 0..8M | Wqkvt 8..11M | Wot 11..13M ; Yb aliases xb after attn
  char* ob = (char*)d_out;
  char* ws = (char*)d_ws;
  const size_t MB = 1024 * 1024;
  unsigned short* QKVb  = (unsigned short*)(ob);
  unsigned short* xb    = (unsigned short*)(ws);
  unsigned short* Wqkvt = (unsigned short*)(ws + 8 * MB);
  unsigned short* Wot   = (unsigned short*)(ws + 11 * MB);
  unsigned short* Yb    = xb;   // x-content dead after QKV gemm

  conv_f32_to_bf16<<<4096, 256, 0, stream>>>(x, xb, 4096 * 1024);
  // pack W_qkv^T rows: [0,1024) = Wq, [1024,1280) = Wk, [1280,1536) = Wv
  transpose_conv4<<<dim3(32, 32, 4), dim3(32, 8), 0, stream>>>(
      Wq, Wk, Wv, Wo,
      Wqkvt, Wqkvt + (size_t)1024 * 1024, Wqkvt + (size_t)1280 * 1024, Wot);

  // fused QKV projection: [4096][1536] bf16 (768 blocks, XCD-chunked)
  gemm_bt<<<dim3(768), 256, 0, stream>>>(xb, Wqkvt, QKVb, 4096, 1536, 1024, 0);

  // RoPE on Q (x0.125) + K in one pass
  rope_qk<<<10240, 256, 0, stream>>>(QKVb, cosb, sinb);

  // attention -> Yb bf16 [B*T][1024]  (1024 heavy-first blocks, 24 KB LDS)
  attn_fused<<<dim3(1024), 256, 0, stream>>>(QKVb, Yb);

  // output projection (fp32, overwrites d_out; 512 blocks, XCD-chunked)
  gemm_bt<<<dim3(512), 256, 0, stream>>>(Yb, Wot, out, 4096, 1024, 1024, 1);
}

// Round 17
// 125.727 us; speedup vs baseline: 1.2520x; 1.2520x over previous
//
#include <hip/hip_runtime.h>
#include <hip/hip_bf16.h>

// Fused causal self-attention (GQA) for MI355X/gfx950.
// Shapes: B=2, T=2048, C=1024, H=16, Hkv=4, D=64.
// Round 17: consolidation — R14 verbatim (best measured: 125.5 us total,
// attn 70.9). R15 (VALU diet) and R16 (K-direct/occupancy) both falsified
// their hypotheses and regressed; the R14 configuration is the empirical
// optimum of this family: paired heavy-first attn grid, K async-LDS dbuf +
// V reg-prefetch dbuf, swapped-QK^T lane-local softmax, XCD-chunked GEMMs.

typedef __attribute__((ext_vector_type(8))) short s16x8;   // 8 x bf16 raw
typedef __attribute__((ext_vector_type(4))) float f32x4;
typedef __attribute__((ext_vector_type(4))) unsigned short u16x4;

#define LOG2E 1.44269504088896340736f

__device__ __forceinline__ float bf2f(unsigned short u) {
  unsigned int i = ((unsigned int)u) << 16;
  return __builtin_bit_cast(float, i);
}
__device__ __forceinline__ unsigned short f2bf(float f) {
  unsigned int i = __builtin_bit_cast(unsigned int, f);
  i += 0x7fffu + ((i >> 16) & 1u);   // RNE
  return (unsigned short)(i >> 16);
}

__device__ __forceinline__ void async16(const void* g, void* l) {
  __builtin_amdgcn_global_load_lds(
      (const __attribute__((address_space(1))) void*)g,
      (__attribute__((address_space(3))) void*)l, 16, 0, 0);
}

// ---------------- prep kernels ----------------

__global__ void conv_f32_to_bf16(const float* __restrict__ in,
                                 unsigned short* __restrict__ out, int n) {
  int i = (blockIdx.x * blockDim.x + threadIdx.x) * 4;
  if (i + 3 < n) {
    float4 v = *(const float4*)(in + i);
    u16x4 o = { f2bf(v.x), f2bf(v.y), f2bf(v.z), f2bf(v.w) };
    *(u16x4*)(out + i) = o;
  }
}

// Batched: W [1024][N_z] fp32 -> Wt [N_z][1024] bf16 for 4 weights in one
// launch (z selects matrix). N: Wq=1024, Wk=256, Wv=256, Wo=1024.
__global__ void transpose_conv4(const float* __restrict__ W0,
                                const float* __restrict__ W1,
                                const float* __restrict__ W2,
                                const float* __restrict__ W3,
                                unsigned short* __restrict__ D0,
                                unsigned short* __restrict__ D1,
                                unsigned short* __restrict__ D2,
                                unsigned short* __restrict__ D3) {
  __shared__ float tile[32][33];
  int z = blockIdx.z;
  const float* W = (z == 0) ? W0 : (z == 1) ? W1 : (z == 2) ? W2 : W3;
  unsigned short* Wt = (z == 0) ? D0 : (z == 1) ? D1 : (z == 2) ? D2 : D3;
  int N = (z == 1 || z == 2) ? 256 : 1024;
  const int K = 1024;
  int n0 = blockIdx.x * 32, k0 = blockIdx.y * 32;
  if (n0 >= N) return;
  int tx = threadIdx.x, ty = threadIdx.y;
  for (int i = ty; i < 32; i += 8)
    tile[i][tx] = W[(size_t)(k0 + i) * N + n0 + tx];
  __syncthreads();
  for (int i = ty; i < 32; i += 8)
    Wt[(size_t)(n0 + i) * K + k0 + tx] = f2bf(tile[tx][i]);
}

// RoPE on packed QKV [4096][1536]: heads 0..15 = Q (scaled 0.125),
// heads 16..19 = K at col offset 1024. t = row % 2048.
__global__ void rope_qk(unsigned short* __restrict__ QKV,
                        const float* __restrict__ cosb,
                        const float* __restrict__ sinb) {
  int idx = blockIdx.x * blockDim.x + threadIdx.x;
  int d = idx & 31;
  int hh = (idx >> 5) % 20;
  int row = idx / (32 * 20);
  int t = row & 2047;
  size_t base;
  float mul;
  if (hh < 16) { base = (size_t)row * 1536 + hh * 64 + d;               mul = 0.125f; }
  else         { base = (size_t)row * 1536 + 1024 + (hh - 16) * 64 + d; mul = 1.0f;   }
  float x1 = bf2f(QKV[base]), x2 = bf2f(QKV[base + 32]);
  float c = cosb[t * 32 + d], s = sinb[t * 32 + d];
  QKV[base]      = f2bf((x1 * c + x2 * s) * mul);
  QKV[base + 32] = f2bf((-x1 * s + x2 * c) * mul);
}

// ---------------- GEMM: C[M,N] = A[M,K] * Bt[N,K]^T ----------------
// 128x64 tile, BK=64, 4 waves (2x2), wave = 64x32 via 4x2x2 16x16x32 MFMA.
// 1D grid with XCD-chunked swizzle (T1): consecutive wg in a chunk share the
// A m-panel -> per-XCD L2 holds 4 A-panels + B = ~4 MB; A refetch 8x -> 1x.
__global__ __launch_bounds__(256) void gemm_bt(
    const unsigned short* __restrict__ A, const unsigned short* __restrict__ Bt,
    void* __restrict__ Cp, int M, int N, int K, int c_f32) {
  __shared__ unsigned short As[128 * 64];   // 16 KB
  __shared__ unsigned short Bs[64 * 64];    // 8 KB
  int tid = threadIdx.x;
  int w = tid >> 6, l = tid & 63, g = l >> 4, lr = l & 15;
  int wr = w >> 1, wc = w & 1;

  // XCD-chunked remap (gridDim.x % 8 == 0 -> bijective)
  int nb = gridDim.x, bid = blockIdx.x;
  int wg = (bid & 7) * (nb >> 3) + (bid >> 3);
  int nx = N >> 6;
  int m0 = (wg / nx) * 128, n0 = (wg % nx) * 64;
  int sk = lr & 7;   // fragment-read swizzle key

  f32x4 acc[4][2] = {};

  for (int k0 = 0; k0 < K; k0 += 64) {
#pragma unroll
    for (int i = 0; i < 4; ++i) {
      int c = i * 256 + tid;             // 16B unit index, 8 units/row
      int row = c >> 3, srcu = ((c & 7) ^ (row & 7)) * 8;
      async16(A + (size_t)(m0 + row) * K + k0 + srcu, (char*)As + c * 16);
    }
#pragma unroll
    for (int i = 0; i < 2; ++i) {
      int c = i * 256 + tid;
      int row = c >> 3, srcu = ((c & 7) ^ (row & 7)) * 8;
      async16(Bt + (size_t)(n0 + row) * K + k0 + srcu, (char*)Bs + c * 16);
    }
    __syncthreads();

    s16x8 af[2][4], bfr[2][2];
#pragma unroll
    for (int ks = 0; ks < 2; ++ks) {
#pragma unroll
      for (int m = 0; m < 4; ++m)
        af[ks][m] = *(const s16x8*)(As + (wr * 64 + m * 16 + lr) * 64 +
                                    ((ks * 4 + g) ^ sk) * 8);
#pragma unroll
      for (int n = 0; n < 2; ++n)
        bfr[ks][n] = *(const s16x8*)(Bs + (wc * 32 + n * 16 + lr) * 64 +
                                     ((ks * 4 + g) ^ sk) * 8);
    }
#pragma unroll
    for (int ks = 0; ks < 2; ++ks)
#pragma unroll
      for (int m = 0; m < 4; ++m)
#pragma unroll
        for (int n = 0; n < 2; ++n)
          acc[m][n] = __builtin_amdgcn_mfma_f32_16x16x32_bf16(
              af[ks][m], bfr[ks][n], acc[m][n], 0, 0, 0);
    __syncthreads();
  }

  // C/D layout: row = (l>>4)*4 + r, col = l&15  [HW-verified]
  if (c_f32) {
    float* C = (float*)Cp;
#pragma unroll
    for (int m = 0; m < 4; ++m)
#pragma unroll
      for (int n = 0; n < 2; ++n)
#pragma unroll
        for (int r = 0; r < 4; ++r)
          C[(size_t)(m0 + wr * 64 + m * 16 + g * 4 + r) * N +
            n0 + wc * 32 + n * 16 + lr] = acc[m][n][r];
  } else {
    unsigned short* C = (unsigned short*)Cp;
#pragma unroll
    for (int m = 0; m < 4; ++m)
#pragma unroll
      for (int n = 0; n < 2; ++n)
#pragma unroll
        for (int r = 0; r < 4; ++r)
          C[(size_t)(m0 + wr * 64 + m * 16 + g * 4 + r) * N +
            n0 + wc * 32 + n * 16 + lr] = f2bf(acc[m][n][r]);
  }
}

// ---------------- flash attention (R9/R14 — best measured) ----------------
// 512 blocks; block n handles q-tile pair (31-ip, ip), ip = n>>5 -> uniform
// 33 tile-iters/block. 4 waves; wave w owns q rows [qt*64+16w, +16).
// KVBLK=64, double-buffered K/V. Lane (g,lr) holds S[q=qw+lr][kv=nf*16+g*4+r].
__global__ __launch_bounds__(256) void attn_fused(
    const unsigned short* __restrict__ QKV, unsigned short* __restrict__ Y) {
  __shared__ unsigned short Kt[2][64 * 64];   // [kv][d], swizzled
  __shared__ unsigned short Vt[2][64 * 64];   // [d][kv], swizzled
  __shared__ unsigned short Pb[4][16 * 64];   // per-wave P [q][kv], swizzled

  const int T = 2048, CS = 1536;
  int tid = threadIdx.x;
  int w = tid >> 6, l = tid & 63, g = l >> 4, lr = l & 15;
  int n = blockIdx.x;
  int ip = n >> 5;                     // pair index 0..15
  int bh = n & 31, b = bh >> 4, h = bh & 15, kvh = h >> 2;
  int sx = lr & 7;

  const unsigned short* Qp = QKV + (size_t)b * T * CS + h * 64;
  const unsigned short* Kp = QKV + (size_t)b * T * CS + 1024 + kvh * 64;
  const unsigned short* Vp = QKV + (size_t)b * T * CS + 1280 + kvh * 64;
  unsigned short* Pw = Pb[w];

  // V steady-state stage decode: c=tid -> d in {0..24}; c=256+tid -> d+32
  int kvA = tid & 63, dA = (tid >> 6) * 8, dB = dA + 32;

  for (int pass = 0; pass < 2; ++pass) {
    int qt = pass == 0 ? (31 - ip) : ip;
    int qw = qt * 64 + w * 16;
    int q_mine = qw + lr;              // this lane's q-row

    s16x8 qf[2];
#pragma unroll
    for (int ks = 0; ks < 2; ++ks)
      qf[ks] = *(const s16x8*)(Qp + (size_t)q_mine * CS + ks * 32 + g * 8);

    f32x4 o[4] = {};
    float mrun = -1e30f, lrun = 0.f;
    int ntiles = qt + 1;

    // ---- prologue: stage tile 0 into buffer 0 ----
#pragma unroll
    for (int i = 0; i < 2; ++i) {
      int c = i * 256 + tid;
      int row = c >> 3, srcc = ((c & 7) ^ (row & 7)) * 8;
      async16(Kp + (size_t)row * CS + srcc, (char*)(&Kt[0][0]) + c * 16);
    }
#pragma unroll
    for (int i = 0; i < 2; ++i) {
      int c = i * 256 + tid;
      int kv = c & 63, d0v = (c >> 6) * 8;
      s16x8 vv = *(const s16x8*)(Vp + (size_t)kv * CS + d0v);
#pragma unroll
      for (int j = 0; j < 8; ++j)
        Vt[0][(d0v + j) * 64 + (kv ^ (j * 8))] = (unsigned short)vv[j];
    }
    __syncthreads();

    int cur = 0;
    for (int it = 0; it < ntiles; ++it) {
      int kv0 = it * 64;
      bool hasnext = (it + 1 < ntiles);

      // ---- T14 stage: issue next tile's K (async->LDS) and V (->regs) ----
      s16x8 vvA, vvB;
      if (hasnext) {
        int kvn = kv0 + 64;
#pragma unroll
        for (int i = 0; i < 2; ++i) {
          int c = i * 256 + tid;
          int row = c >> 3, srcc = ((c & 7) ^ (row & 7)) * 8;
          async16(Kp + (size_t)(kvn + row) * CS + srcc,
                  (char*)(&Kt[cur ^ 1][0]) + c * 16);
        }
        vvA = *(const s16x8*)(Vp + (size_t)(kvn + kvA) * CS + dA);
        vvB = *(const s16x8*)(Vp + (size_t)(kvn + kvA) * CS + dB);
      }

      // ---- S^T = K Q^T: lane holds S[q_mine][kv = nf*16 + g*4 + r] ----
      const unsigned short* Kc = &Kt[cur][0];
      const unsigned short* Vc = &Vt[cur][0];
      f32x4 s[4];
      __builtin_amdgcn_s_setprio(1);
#pragma unroll
      for (int nf = 0; nf < 4; ++nf) {
        f32x4 z = {};
#pragma unroll
        for (int ks = 0; ks < 2; ++ks) {
          s16x8 kf = *(const s16x8*)(Kc + (nf * 16 + lr) * 64 +
                                     ((ks * 4 + g) ^ sx) * 8);
          z = __builtin_amdgcn_mfma_f32_16x16x32_bf16(kf, qf[ks], z, 0, 0, 0);
        }
        s[nf] = z;
      }
      __builtin_amdgcn_s_setprio(0);

      if (it == ntiles - 1) {   // diagonal tile: causal mask
#pragma unroll
        for (int nf = 0; nf < 4; ++nf)
#pragma unroll
          for (int r = 0; r < 4; ++r)
            if (kv0 + nf * 16 + g * 4 + r > q_mine) s[nf][r] = -1e30f;
      }

      // ---- softmax: 16 in-lane values + 2 shuffles ----
      float mt = s[0][0];
#pragma unroll
      for (int nf = 0; nf < 4; ++nf)
#pragma unroll
        for (int r = 0; r < 4; ++r) mt = fmaxf(mt, s[nf][r]);
      mt = fmaxf(mt, __shfl_xor(mt, 16, 64));
      mt = fmaxf(mt, __shfl_xor(mt, 32, 64));

      if (__any(mt > mrun + 8.f)) {    // wave-uniform rescale (defer-max)
        float mnew = fmaxf(mrun, mt);
        float corr = exp2f((mrun - mnew) * LOG2E);
        float psum = 0.f;
#pragma unroll
        for (int nf = 0; nf < 4; ++nf)
#pragma unroll
          for (int r = 0; r < 4; ++r) {
            float p = exp2f((s[nf][r] - mnew) * LOG2E);
            s[nf][r] = p;
            psum += p;
          }
        psum += __shfl_xor(psum, 16, 64);
        psum += __shfl_xor(psum, 32, 64);
        lrun = lrun * corr + psum;
        mrun = mnew;
#pragma unroll
        for (int r = 0; r < 4; ++r) {
          float cr = __shfl(corr, g * 4 + r, 64);
#pragma unroll
          for (int d0 = 0; d0 < 4; ++d0) o[d0][r] *= cr;
        }
      } else {                         // fast path: no rescale
        float psum = 0.f;
#pragma unroll
        for (int nf = 0; nf < 4; ++nf)
#pragma unroll
          for (int r = 0; r < 4; ++r) {
            float p = exp2f((s[nf][r] - mrun) * LOG2E);
            s[nf][r] = p;
            psum += p;
          }
        psum += __shfl_xor(psum, 16, 64);
        psum += __shfl_xor(psum, 32, 64);
        lrun += psum;
      }

      // ---- P -> LDS [q=lr][kv], packed b64 writes (r 0..3 contiguous) ----
#pragma unroll
      for (int nf = 0; nf < 4; ++nf) {
        u16x4 pv = { f2bf(s[nf][0]), f2bf(s[nf][1]),
                     f2bf(s[nf][2]), f2bf(s[nf][3]) };
        *(u16x4*)(Pw + lr * 64 + ((nf * 16 + g * 4) ^ (sx * 8))) = pv;
      }
      asm volatile("s_waitcnt lgkmcnt(0)" ::: "memory");
      __builtin_amdgcn_sched_barrier(0);   // rule #18

      s16x8 pf[2];
#pragma unroll
      for (int ks = 0; ks < 2; ++ks)
        pf[ks] = *(const s16x8*)(Pw + lr * 64 + ((ks * 4 + g) ^ sx) * 8);
      __builtin_amdgcn_s_setprio(1);
#pragma unroll
      for (int d0 = 0; d0 < 4; ++d0)
#pragma unroll
        for (int ks = 0; ks < 2; ++ks) {
          s16x8 vf = *(const s16x8*)(Vc + (d0 * 16 + lr) * 64 +
                                     ((ks * 4 + g) ^ sx) * 8);
          o[d0] = __builtin_amdgcn_mfma_f32_16x16x32_bf16(pf[ks], vf, o[d0], 0, 0, 0);
        }
      __builtin_amdgcn_s_setprio(0);

      // ---- write staged V regs -> back buffer ----
      if (hasnext) {
#pragma unroll
        for (int j = 0; j < 8; ++j)
          Vt[cur ^ 1][(dA + j) * 64 + (kvA ^ (j * 8))] = (unsigned short)vvA[j];
#pragma unroll
        for (int j = 0; j < 8; ++j)
          Vt[cur ^ 1][(dB + j) * 64 + (kvA ^ (j * 8))] = (unsigned short)vvB[j];
      }
      __syncthreads();   // drains vmcnt (K async) + lgkm (V writes)
      cur ^= 1;
    }

    // ---- epilogue: o rows are g*4+r; lrun lives at lane (*, lr=g*4+r) ----
#pragma unroll
    for (int r = 0; r < 4; ++r) {
      float lv = __shfl(lrun, g * 4 + r, 64);
      float inv = 1.f / lv;
      size_t rowoff = (size_t)(b * T + qw + g * 4 + r) * 1024 + h * 64;
#pragma unroll
      for (int d0 = 0; d0 < 4; ++d0)
        Y[rowoff + d0 * 16 + lr] = f2bf(o[d0][r] * inv);
    }
  }
}

// ---------------- launch ----------------

extern "C" void kernel_launch(void* const* d_in, const int* in_sizes, int n_in,
                              void* d_out, int out_size, void* d_ws, size_t ws_size,
                              hipStream_t stream) {
  const float* x    = (const float*)d_in[0];
  const float* cosb = (const float*)d_in[1];
  const float* sinb = (const float*)d_in[2];
  const float* Wq   = (const float*)d_in[3];
  const float* Wk   = (const float*)d_in[4];
  const float* Wv   = (const float*)d_in[5];
  const float* Wo   = (const float*)d_in[6];
  float* out = (float*)d_out;

  // Buffer map:
  //   d_out (16 MB): QKVb [4096][1536] bf16 = 12 MB  (dead at final gemm)
  //   d_ws: xb 0..8M | Wqkvt 8..11M | Wot 11..13M ; Yb aliases xb after attn
  char* ob = (char*)d_out;
  char* ws = (char*)d_ws;
  const size_t MB = 1024 * 1024;
  unsigned short* QKVb  = (unsigned short*)(ob);
  unsigned short* xb    = (unsigned short*)(ws);
  unsigned short* Wqkvt = (unsigned short*)(ws + 8 * MB);
  unsigned short* Wot   = (unsigned short*)(ws + 11 * MB);
  unsigned short* Yb    = xb;   // x-content dead after QKV gemm

  conv_f32_to_bf16<<<4096, 256, 0, stream>>>(x, xb, 4096 * 1024);
  // pack W_qkv^T rows: [0,1024) = Wq, [1024,1280) = Wk, [1280,1536) = Wv
  transpose_conv4<<<dim3(32, 32, 4), dim3(32, 8), 0, stream>>>(
      Wq, Wk, Wv, Wo,
      Wqkvt, Wqkvt + (size_t)1024 * 1024, Wqkvt + (size_t)1280 * 1024, Wot);

  // fused QKV projection: [4096][1536] bf16 (768 blocks, XCD-chunked)
  gemm_bt<<<dim3(768), 256, 0, stream>>>(xb, Wqkvt, QKVb, 4096, 1536, 1024, 0);

  // RoPE on Q (x0.125) + K in one pass
  rope_qk<<<10240, 256, 0, stream>>>(QKVb, cosb, sinb);

  // attention -> Yb bf16 [B*T][1024]  (R9/R14 verbatim)
  attn_fused<<<dim3(512), 256, 0, stream>>>(QKVb, Yb);

  // output projection (fp32, overwrites d_out; 512 blocks, XCD-chunked)
  gemm_bt<<<dim3(512), 256, 0, stream>>>(Yb, Wot, out, 4096, 1024, 1024, 1);
}

// Round 18
// 123.204 us; speedup vs baseline: 1.2776x; 1.0205x over previous
//
#include <hip/hip_runtime.h>
#include <hip/hip_bf16.h>

// Fused causal self-attention (GQA) for MI355X/gfx950.
// Shapes: B=2, T=2048, C=1024, H=16, Hkv=4, D=64.
// Round 18: R17 (=R14, best measured) + two isolated per-iter op-count cuts:
// (1) P-pack via v_cvt_pk_bf16_f32 (8 ops replace 64 VALU RNE ops/iter);
// (2) V staging re-decoded to kv-pairs -> 8 ds_write_b32 replace 16 b16
//     (store rule Vt[d][kv^((d&7)*8)] preserved; banks 2-way = free).
// Everything else byte-identical to R17.

typedef __attribute__((ext_vector_type(8))) short s16x8;   // 8 x bf16 raw
typedef __attribute__((ext_vector_type(4))) float f32x4;
typedef __attribute__((ext_vector_type(4))) unsigned short u16x4;

#define LOG2E 1.44269504088896340736f

__device__ __forceinline__ float bf2f(unsigned short u) {
  unsigned int i = ((unsigned int)u) << 16;
  return __builtin_bit_cast(float, i);
}
__device__ __forceinline__ unsigned short f2bf(float f) {
  unsigned int i = __builtin_bit_cast(unsigned int, f);
  i += 0x7fffu + ((i >> 16) & 1u);   // RNE
  return (unsigned short)(i >> 16);
}
__device__ __forceinline__ unsigned int cvtpk(float lo, float hi) {
  unsigned int r;                    // low half <- lo, high half <- hi (HW-verified R10-12)
  asm("v_cvt_pk_bf16_f32 %0, %1, %2" : "=v"(r) : "v"(lo), "v"(hi));
  return r;
}

__device__ __forceinline__ void async16(const void* g, void* l) {
  __builtin_amdgcn_global_load_lds(
      (const __attribute__((address_space(1))) void*)g,
      (__attribute__((address_space(3))) void*)l, 16, 0, 0);
}

// ---------------- prep kernels ----------------

__global__ void conv_f32_to_bf16(const float* __restrict__ in,
                                 unsigned short* __restrict__ out, int n) {
  int i = (blockIdx.x * blockDim.x + threadIdx.x) * 4;
  if (i + 3 < n) {
    float4 v = *(const float4*)(in + i);
    u16x4 o = { f2bf(v.x), f2bf(v.y), f2bf(v.z), f2bf(v.w) };
    *(u16x4*)(out + i) = o;
  }
}

// Batched: W [1024][N_z] fp32 -> Wt [N_z][1024] bf16 for 4 weights in one
// launch (z selects matrix). N: Wq=1024, Wk=256, Wv=256, Wo=1024.
__global__ void transpose_conv4(const float* __restrict__ W0,
                                const float* __restrict__ W1,
                                const float* __restrict__ W2,
                                const float* __restrict__ W3,
                                unsigned short* __restrict__ D0,
                                unsigned short* __restrict__ D1,
                                unsigned short* __restrict__ D2,
                                unsigned short* __restrict__ D3) {
  __shared__ float tile[32][33];
  int z = blockIdx.z;
  const float* W = (z == 0) ? W0 : (z == 1) ? W1 : (z == 2) ? W2 : W3;
  unsigned short* Wt = (z == 0) ? D0 : (z == 1) ? D1 : (z == 2) ? D2 : D3;
  int N = (z == 1 || z == 2) ? 256 : 1024;
  const int K = 1024;
  int n0 = blockIdx.x * 32, k0 = blockIdx.y * 32;
  if (n0 >= N) return;
  int tx = threadIdx.x, ty = threadIdx.y;
  for (int i = ty; i < 32; i += 8)
    tile[i][tx] = W[(size_t)(k0 + i) * N + n0 + tx];
  __syncthreads();
  for (int i = ty; i < 32; i += 8)
    Wt[(size_t)(n0 + i) * K + k0 + tx] = f2bf(tile[tx][i]);
}

// RoPE on packed QKV [4096][1536]: heads 0..15 = Q (scaled 0.125),
// heads 16..19 = K at col offset 1024. t = row % 2048.
__global__ void rope_qk(unsigned short* __restrict__ QKV,
                        const float* __restrict__ cosb,
                        const float* __restrict__ sinb) {
  int idx = blockIdx.x * blockDim.x + threadIdx.x;
  int d = idx & 31;
  int hh = (idx >> 5) % 20;
  int row = idx / (32 * 20);
  int t = row & 2047;
  size_t base;
  float mul;
  if (hh < 16) { base = (size_t)row * 1536 + hh * 64 + d;               mul = 0.125f; }
  else         { base = (size_t)row * 1536 + 1024 + (hh - 16) * 64 + d; mul = 1.0f;   }
  float x1 = bf2f(QKV[base]), x2 = bf2f(QKV[base + 32]);
  float c = cosb[t * 32 + d], s = sinb[t * 32 + d];
  QKV[base]      = f2bf((x1 * c + x2 * s) * mul);
  QKV[base + 32] = f2bf((-x1 * s + x2 * c) * mul);
}

// ---------------- GEMM: C[M,N] = A[M,K] * Bt[N,K]^T (R14 verbatim) ----------------
// 128x64 tile, BK=64, 4 waves (2x2), wave = 64x32 via 4x2x2 16x16x32 MFMA.
// 1D grid with XCD-chunked swizzle (T1).
__global__ __launch_bounds__(256) void gemm_bt(
    const unsigned short* __restrict__ A, const unsigned short* __restrict__ Bt,
    void* __restrict__ Cp, int M, int N, int K, int c_f32) {
  __shared__ unsigned short As[128 * 64];   // 16 KB
  __shared__ unsigned short Bs[64 * 64];    // 8 KB
  int tid = threadIdx.x;
  int w = tid >> 6, l = tid & 63, g = l >> 4, lr = l & 15;
  int wr = w >> 1, wc = w & 1;

  // XCD-chunked remap (gridDim.x % 8 == 0 -> bijective)
  int nb = gridDim.x, bid = blockIdx.x;
  int wg = (bid & 7) * (nb >> 3) + (bid >> 3);
  int nx = N >> 6;
  int m0 = (wg / nx) * 128, n0 = (wg % nx) * 64;
  int sk = lr & 7;   // fragment-read swizzle key

  f32x4 acc[4][2] = {};

  for (int k0 = 0; k0 < K; k0 += 64) {
#pragma unroll
    for (int i = 0; i < 4; ++i) {
      int c = i * 256 + tid;             // 16B unit index, 8 units/row
      int row = c >> 3, srcu = ((c & 7) ^ (row & 7)) * 8;
      async16(A + (size_t)(m0 + row) * K + k0 + srcu, (char*)As + c * 16);
    }
#pragma unroll
    for (int i = 0; i < 2; ++i) {
      int c = i * 256 + tid;
      int row = c >> 3, srcu = ((c & 7) ^ (row & 7)) * 8;
      async16(Bt + (size_t)(n0 + row) * K + k0 + srcu, (char*)Bs + c * 16);
    }
    __syncthreads();

    s16x8 af[2][4], bfr[2][2];
#pragma unroll
    for (int ks = 0; ks < 2; ++ks) {
#pragma unroll
      for (int m = 0; m < 4; ++m)
        af[ks][m] = *(const s16x8*)(As + (wr * 64 + m * 16 + lr) * 64 +
                                    ((ks * 4 + g) ^ sk) * 8);
#pragma unroll
      for (int n = 0; n < 2; ++n)
        bfr[ks][n] = *(const s16x8*)(Bs + (wc * 32 + n * 16 + lr) * 64 +
                                     ((ks * 4 + g) ^ sk) * 8);
    }
#pragma unroll
    for (int ks = 0; ks < 2; ++ks)
#pragma unroll
      for (int m = 0; m < 4; ++m)
#pragma unroll
        for (int n = 0; n < 2; ++n)
          acc[m][n] = __builtin_amdgcn_mfma_f32_16x16x32_bf16(
              af[ks][m], bfr[ks][n], acc[m][n], 0, 0, 0);
    __syncthreads();
  }

  // C/D layout: row = (l>>4)*4 + r, col = l&15  [HW-verified]
  if (c_f32) {
    float* C = (float*)Cp;
#pragma unroll
    for (int m = 0; m < 4; ++m)
#pragma unroll
      for (int n = 0; n < 2; ++n)
#pragma unroll
        for (int r = 0; r < 4; ++r)
          C[(size_t)(m0 + wr * 64 + m * 16 + g * 4 + r) * N +
            n0 + wc * 32 + n * 16 + lr] = acc[m][n][r];
  } else {
    unsigned short* C = (unsigned short*)Cp;
#pragma unroll
    for (int m = 0; m < 4; ++m)
#pragma unroll
      for (int n = 0; n < 2; ++n)
#pragma unroll
        for (int r = 0; r < 4; ++r)
          C[(size_t)(m0 + wr * 64 + m * 16 + g * 4 + r) * N +
            n0 + wc * 32 + n * 16 + lr] = f2bf(acc[m][n][r]);
  }
}

// ---------------- flash attention (R14 structure + 2 op-count cuts) ----------------
// 512 blocks; block n handles q-tile pair (31-ip, ip), ip = n>>5 -> uniform
// 33 tile-iters/block. 4 waves; wave w owns q rows [qt*64+16w, +16).
// KVBLK=64, double-buffered K/V. Lane (g,lr) holds S[q=qw+lr][kv=nf*16+g*4+r].
__global__ __launch_bounds__(256) void attn_fused(
    const unsigned short* __restrict__ QKV, unsigned short* __restrict__ Y) {
  __shared__ unsigned short Kt[2][64 * 64];   // [kv][d], swizzled
  __shared__ unsigned short Vt[2][64 * 64];   // [d][kv], swizzled
  __shared__ unsigned short Pb[4][16 * 64];   // per-wave P [q][kv], swizzled

  const int T = 2048, CS = 1536;
  int tid = threadIdx.x;
  int w = tid >> 6, l = tid & 63, g = l >> 4, lr = l & 15;
  int n = blockIdx.x;
  int ip = n >> 5;                     // pair index 0..15
  int bh = n & 31, b = bh >> 4, h = bh & 15, kvh = h >> 2;
  int sx = lr & 7;

  const unsigned short* Qp = QKV + (size_t)b * T * CS + h * 64;
  const unsigned short* Kp = QKV + (size_t)b * T * CS + 1024 + kvh * 64;
  const unsigned short* Vp = QKV + (size_t)b * T * CS + 1280 + kvh * 64;
  unsigned short* Pw = Pb[w];

  // V staging decode (R18): thread owns kv-pair (kvE, kvE+1) x d-chunk dcV.
  // Store rule Vt[d][kv ^ ((d&7)*8)] preserved; (2k+1)^(j*8) = (2k)^(j*8)+1
  // -> b32-packed writes, 4B-aligned, banks k^(j*4) = 32-distinct (2-way free).
  int kvE = (tid & 31) * 2, dcV = ((tid >> 5) & 7) * 8;

  for (int pass = 0; pass < 2; ++pass) {
    int qt = pass == 0 ? (31 - ip) : ip;
    int qw = qt * 64 + w * 16;
    int q_mine = qw + lr;              // this lane's q-row

    s16x8 qf[2];
#pragma unroll
    for (int ks = 0; ks < 2; ++ks)
      qf[ks] = *(const s16x8*)(Qp + (size_t)q_mine * CS + ks * 32 + g * 8);

    f32x4 o[4] = {};
    float mrun = -1e30f, lrun = 0.f;
    int ntiles = qt + 1;

    // ---- prologue: stage tile 0 into buffer 0 ----
#pragma unroll
    for (int i = 0; i < 2; ++i) {
      int c = i * 256 + tid;
      int row = c >> 3, srcc = ((c & 7) ^ (row & 7)) * 8;
      async16(Kp + (size_t)row * CS + srcc, (char*)(&Kt[0][0]) + c * 16);
    }
    {
      s16x8 vE = *(const s16x8*)(Vp + (size_t)kvE * CS + dcV);
      s16x8 vO = *(const s16x8*)(Vp + (size_t)(kvE + 1) * CS + dcV);
#pragma unroll
      for (int j = 0; j < 8; ++j) {
        unsigned int pk = (unsigned int)(unsigned short)vE[j] |
                          ((unsigned int)(unsigned short)vO[j] << 16);
        *(unsigned int*)(&Vt[0][0] + (dcV + j) * 64 + (kvE ^ (j * 8))) = pk;
      }
    }
    __syncthreads();

    int cur = 0;
    for (int it = 0; it < ntiles; ++it) {
      int kv0 = it * 64;
      bool hasnext = (it + 1 < ntiles);

      // ---- T14 stage: issue next tile's K (async->LDS) and V (->regs) ----
      s16x8 vE, vO;
      if (hasnext) {
        int kvn = kv0 + 64;
#pragma unroll
        for (int i = 0; i < 2; ++i) {
          int c = i * 256 + tid;
          int row = c >> 3, srcc = ((c & 7) ^ (row & 7)) * 8;
          async16(Kp + (size_t)(kvn + row) * CS + srcc,
                  (char*)(&Kt[cur ^ 1][0]) + c * 16);
        }
        vE = *(const s16x8*)(Vp + (size_t)(kvn + kvE) * CS + dcV);
        vO = *(const s16x8*)(Vp + (size_t)(kvn + kvE + 1) * CS + dcV);
      }

      // ---- S^T = K Q^T: lane holds S[q_mine][kv = nf*16 + g*4 + r] ----
      const unsigned short* Kc = &Kt[cur][0];
      const unsigned short* Vc = &Vt[cur][0];
      f32x4 s[4];
      __builtin_amdgcn_s_setprio(1);
#pragma unroll
      for (int nf = 0; nf < 4; ++nf) {
        f32x4 z = {};
#pragma unroll
        for (int ks = 0; ks < 2; ++ks) {
          s16x8 kf = *(const s16x8*)(Kc + (nf * 16 + lr) * 64 +
                                     ((ks * 4 + g) ^ sx) * 8);
          z = __builtin_amdgcn_mfma_f32_16x16x32_bf16(kf, qf[ks], z, 0, 0, 0);
        }
        s[nf] = z;
      }
      __builtin_amdgcn_s_setprio(0);

      if (it == ntiles - 1) {   // diagonal tile: causal mask
#pragma unroll
        for (int nf = 0; nf < 4; ++nf)
#pragma unroll
          for (int r = 0; r < 4; ++r)
            if (kv0 + nf * 16 + g * 4 + r > q_mine) s[nf][r] = -1e30f;
      }

      // ---- softmax: 16 in-lane values + 2 shuffles ----
      float mt = s[0][0];
#pragma unroll
      for (int nf = 0; nf < 4; ++nf)
#pragma unroll
        for (int r = 0; r < 4; ++r) mt = fmaxf(mt, s[nf][r]);
      mt = fmaxf(mt, __shfl_xor(mt, 16, 64));
      mt = fmaxf(mt, __shfl_xor(mt, 32, 64));

      if (__any(mt > mrun + 8.f)) {    // wave-uniform rescale (defer-max)
        float mnew = fmaxf(mrun, mt);
        float corr = exp2f((mrun - mnew) * LOG2E);
        float psum = 0.f;
#pragma unroll
        for (int nf = 0; nf < 4; ++nf)
#pragma unroll
          for (int r = 0; r < 4; ++r) {
            float p = exp2f((s[nf][r] - mnew) * LOG2E);
            s[nf][r] = p;
            psum += p;
          }
        psum += __shfl_xor(psum, 16, 64);
        psum += __shfl_xor(psum, 32, 64);
        lrun = lrun * corr + psum;
        mrun = mnew;
#pragma unroll
        for (int r = 0; r < 4; ++r) {
          float cr = __shfl(corr, g * 4 + r, 64);
#pragma unroll
          for (int d0 = 0; d0 < 4; ++d0) o[d0][r] *= cr;
        }
      } else {                         // fast path: no rescale
        float psum = 0.f;
#pragma unroll
        for (int nf = 0; nf < 4; ++nf)
#pragma unroll
          for (int r = 0; r < 4; ++r) {
            float p = exp2f((s[nf][r] - mrun) * LOG2E);
            s[nf][r] = p;
            psum += p;
          }
        psum += __shfl_xor(psum, 16, 64);
        psum += __shfl_xor(psum, 32, 64);
        lrun += psum;
      }

      // ---- P -> LDS [q=lr][kv] via cvt_pk (b64 writes; RNE identical) ----
#pragma unroll
      for (int nf = 0; nf < 4; ++nf) {
        uint2 pv;
        pv.x = cvtpk(s[nf][0], s[nf][1]);
        pv.y = cvtpk(s[nf][2], s[nf][3]);
        *(uint2*)(Pw + lr * 64 + ((nf * 16 + g * 4) ^ (sx * 8))) = pv;
      }
      asm volatile("s_waitcnt lgkmcnt(0)" ::: "memory");
      __builtin_amdgcn_sched_barrier(0);   // rule #18

      s16x8 pf[2];
#pragma unroll
      for (int ks = 0; ks < 2; ++ks)
        pf[ks] = *(const s16x8*)(Pw + lr * 64 + ((ks * 4 + g) ^ sx) * 8);
      __builtin_amdgcn_s_setprio(1);
#pragma unroll
      for (int d0 = 0; d0 < 4; ++d0)
#pragma unroll
        for (int ks = 0; ks < 2; ++ks) {
          s16x8 vf = *(const s16x8*)(Vc + (d0 * 16 + lr) * 64 +
                                     ((ks * 4 + g) ^ sx) * 8);
          o[d0] = __builtin_amdgcn_mfma_f32_16x16x32_bf16(pf[ks], vf, o[d0], 0, 0, 0);
        }
      __builtin_amdgcn_s_setprio(0);

      // ---- write staged V regs -> back buffer (8x b32 packed) ----
      if (hasnext) {
        unsigned short* Vn = &Vt[cur ^ 1][0];
#pragma unroll
        for (int j = 0; j < 8; ++j) {
          unsigned int pk = (unsigned int)(unsigned short)vE[j] |
                            ((unsigned int)(unsigned short)vO[j] << 16);
          *(unsigned int*)(Vn + (dcV + j) * 64 + (kvE ^ (j * 8))) = pk;
        }
      }
      __syncthreads();   // drains vmcnt (K async) + lgkm (V writes)
      cur ^= 1;
    }

    // ---- epilogue: o rows are g*4+r; lrun lives at lane (*, lr=g*4+r) ----
#pragma unroll
    for (int r = 0; r < 4; ++r) {
      float lv = __shfl(lrun, g * 4 + r, 64);
      float inv = 1.f / lv;
      size_t rowoff = (size_t)(b * T + qw + g * 4 + r) * 1024 + h * 64;
#pragma unroll
      for (int d0 = 0; d0 < 4; ++d0)
        Y[rowoff + d0 * 16 + lr] = f2bf(o[d0][r] * inv);
    }
  }
}

// ---------------- launch ----------------

extern "C" void kernel_launch(void* const* d_in, const int* in_sizes, int n_in,
                              void* d_out, int out_size, void* d_ws, size_t ws_size,
                              hipStream_t stream) {
  const float* x    = (const float*)d_in[0];
  const float* cosb = (const float*)d_in[1];
  const float* sinb = (const float*)d_in[2];
  const float* Wq   = (const float*)d_in[3];
  const float* Wk   = (const float*)d_in[4];
  const float* Wv   = (const float*)d_in[5];
  const float* Wo   = (const float*)d_in[6];
  float* out = (float*)d_out;

  // Buffer map:
  //   d_out (16 MB): QKVb [4096][1536] bf16 = 12 MB  (dead at final gemm)
  //   d_ws: xb 0..8M | Wqkvt 8..11M | Wot 11..13M ; Yb aliases xb after attn
  char* ob = (char*)d_out;
  char* ws = (char*)d_ws;
  const size_t MB = 1024 * 1024;
  unsigned short* QKVb  = (unsigned short*)(ob);
  unsigned short* xb    = (unsigned short*)(ws);
  unsigned short* Wqkvt = (unsigned short*)(ws + 8 * MB);
  unsigned short* Wot   = (unsigned short*)(ws + 11 * MB);
  unsigned short* Yb    = xb;   // x-content dead after QKV gemm

  conv_f32_to_bf16<<<4096, 256, 0, stream>>>(x, xb, 4096 * 1024);
  // pack W_qkv^T rows: [0,1024) = Wq, [1024,1280) = Wk, [1280,1536) = Wv
  transpose_conv4<<<dim3(32, 32, 4), dim3(32, 8), 0, stream>>>(
      Wq, Wk, Wv, Wo,
      Wqkvt, Wqkvt + (size_t)1024 * 1024, Wqkvt + (size_t)1280 * 1024, Wot);

  // fused QKV projection: [4096][1536] bf16 (768 blocks, XCD-chunked)
  gemm_bt<<<dim3(768), 256, 0, stream>>>(xb, Wqkvt, QKVb, 4096, 1536, 1024, 0);

  // RoPE on Q (x0.125) + K in one pass
  rope_qk<<<10240, 256, 0, stream>>>(QKVb, cosb, sinb);

  // attention -> Yb bf16 [B*T][1024]
  attn_fused<<<dim3(512), 256, 0, stream>>>(QKVb, Yb);

  // output projection (fp32, overwrites d_out; 512 blocks, XCD-chunked)
  gemm_bt<<<dim3(512), 256, 0, stream>>>(Yb, Wot, out, 4096, 1024, 1024, 1);
}

// Round 19
// 122.037 us; speedup vs baseline: 1.2899x; 1.0096x over previous
//
#include <hip/hip_runtime.h>
#include <hip/hip_bf16.h>

// Fused causal self-attention (GQA) for MI355X/gfx950.
// Shapes: B=2, T=2048, C=1024, H=16, Hkv=4, D=64.
// Round 19: R18 + single change — exp2-domain softmax. 0.125*log2(e) folded
// into the Q RoPE scale, so QK^T scores are already in log2 units: every
// exp2f((x)*LOG2E) becomes exp2f(x) (kills ~34 v_mul/iter), defer threshold
// 8 nats -> 11.5416 log2-units. Numerics verified identical in R10-R12.

typedef __attribute__((ext_vector_type(8))) short s16x8;   // 8 x bf16 raw
typedef __attribute__((ext_vector_type(4))) float f32x4;
typedef __attribute__((ext_vector_type(4))) unsigned short u16x4;

#define LOG2E 1.44269504088896340736f

__device__ __forceinline__ float bf2f(unsigned short u) {
  unsigned int i = ((unsigned int)u) << 16;
  return __builtin_bit_cast(float, i);
}
__device__ __forceinline__ unsigned short f2bf(float f) {
  unsigned int i = __builtin_bit_cast(unsigned int, f);
  i += 0x7fffu + ((i >> 16) & 1u);   // RNE
  return (unsigned short)(i >> 16);
}
__device__ __forceinline__ unsigned int cvtpk(float lo, float hi) {
  unsigned int r;                    // low half <- lo, high half <- hi (HW-verified)
  asm("v_cvt_pk_bf16_f32 %0, %1, %2" : "=v"(r) : "v"(lo), "v"(hi));
  return r;
}

__device__ __forceinline__ void async16(const void* g, void* l) {
  __builtin_amdgcn_global_load_lds(
      (const __attribute__((address_space(1))) void*)g,
      (__attribute__((address_space(3))) void*)l, 16, 0, 0);
}

// ---------------- prep kernels ----------------

__global__ void conv_f32_to_bf16(const float* __restrict__ in,
                                 unsigned short* __restrict__ out, int n) {
  int i = (blockIdx.x * blockDim.x + threadIdx.x) * 4;
  if (i + 3 < n) {
    float4 v = *(const float4*)(in + i);
    u16x4 o = { f2bf(v.x), f2bf(v.y), f2bf(v.z), f2bf(v.w) };
    *(u16x4*)(out + i) = o;
  }
}

// Batched: W [1024][N_z] fp32 -> Wt [N_z][1024] bf16 for 4 weights in one
// launch (z selects matrix). N: Wq=1024, Wk=256, Wv=256, Wo=1024.
__global__ void transpose_conv4(const float* __restrict__ W0,
                                const float* __restrict__ W1,
                                const float* __restrict__ W2,
                                const float* __restrict__ W3,
                                unsigned short* __restrict__ D0,
                                unsigned short* __restrict__ D1,
                                unsigned short* __restrict__ D2,
                                unsigned short* __restrict__ D3) {
  __shared__ float tile[32][33];
  int z = blockIdx.z;
  const float* W = (z == 0) ? W0 : (z == 1) ? W1 : (z == 2) ? W2 : W3;
  unsigned short* Wt = (z == 0) ? D0 : (z == 1) ? D1 : (z == 2) ? D2 : D3;
  int N = (z == 1 || z == 2) ? 256 : 1024;
  const int K = 1024;
  int n0 = blockIdx.x * 32, k0 = blockIdx.y * 32;
  if (n0 >= N) return;
  int tx = threadIdx.x, ty = threadIdx.y;
  for (int i = ty; i < 32; i += 8)
    tile[i][tx] = W[(size_t)(k0 + i) * N + n0 + tx];
  __syncthreads();
  for (int i = ty; i < 32; i += 8)
    Wt[(size_t)(n0 + i) * K + k0 + tx] = f2bf(tile[tx][i]);
}

// RoPE on packed QKV [4096][1536]: heads 0..15 = Q scaled 0.125*log2(e)
// (softmax runs in exp2 domain), heads 16..19 = K at col offset 1024.
__global__ void rope_qk(unsigned short* __restrict__ QKV,
                        const float* __restrict__ cosb,
                        const float* __restrict__ sinb) {
  int idx = blockIdx.x * blockDim.x + threadIdx.x;
  int d = idx & 31;
  int hh = (idx >> 5) % 20;
  int row = idx / (32 * 20);
  int t = row & 2047;
  size_t base;
  float mul;
  if (hh < 16) { base = (size_t)row * 1536 + hh * 64 + d;   mul = 0.125f * LOG2E; }
  else         { base = (size_t)row * 1536 + 1024 + (hh - 16) * 64 + d; mul = 1.0f; }
  float x1 = bf2f(QKV[base]), x2 = bf2f(QKV[base + 32]);
  float c = cosb[t * 32 + d], s = sinb[t * 32 + d];
  QKV[base]      = f2bf((x1 * c + x2 * s) * mul);
  QKV[base + 32] = f2bf((-x1 * s + x2 * c) * mul);
}

// ---------------- GEMM: C[M,N] = A[M,K] * Bt[N,K]^T (R14 verbatim) ----------------
// 128x64 tile, BK=64, 4 waves (2x2), wave = 64x32 via 4x2x2 16x16x32 MFMA.
// 1D grid with XCD-chunked swizzle (T1).
__global__ __launch_bounds__(256) void gemm_bt(
    const unsigned short* __restrict__ A, const unsigned short* __restrict__ Bt,
    void* __restrict__ Cp, int M, int N, int K, int c_f32) {
  __shared__ unsigned short As[128 * 64];   // 16 KB
  __shared__ unsigned short Bs[64 * 64];    // 8 KB
  int tid = threadIdx.x;
  int w = tid >> 6, l = tid & 63, g = l >> 4, lr = l & 15;
  int wr = w >> 1, wc = w & 1;

  // XCD-chunked remap (gridDim.x % 8 == 0 -> bijective)
  int nb = gridDim.x, bid = blockIdx.x;
  int wg = (bid & 7) * (nb >> 3) + (bid >> 3);
  int nx = N >> 6;
  int m0 = (wg / nx) * 128, n0 = (wg % nx) * 64;
  int sk = lr & 7;   // fragment-read swizzle key

  f32x4 acc[4][2] = {};

  for (int k0 = 0; k0 < K; k0 += 64) {
#pragma unroll
    for (int i = 0; i < 4; ++i) {
      int c = i * 256 + tid;             // 16B unit index, 8 units/row
      int row = c >> 3, srcu = ((c & 7) ^ (row & 7)) * 8;
      async16(A + (size_t)(m0 + row) * K + k0 + srcu, (char*)As + c * 16);
    }
#pragma unroll
    for (int i = 0; i < 2; ++i) {
      int c = i * 256 + tid;
      int row = c >> 3, srcu = ((c & 7) ^ (row & 7)) * 8;
      async16(Bt + (size_t)(n0 + row) * K + k0 + srcu, (char*)Bs + c * 16);
    }
    __syncthreads();

    s16x8 af[2][4], bfr[2][2];
#pragma unroll
    for (int ks = 0; ks < 2; ++ks) {
#pragma unroll
      for (int m = 0; m < 4; ++m)
        af[ks][m] = *(const s16x8*)(As + (wr * 64 + m * 16 + lr) * 64 +
                                    ((ks * 4 + g) ^ sk) * 8);
#pragma unroll
      for (int n = 0; n < 2; ++n)
        bfr[ks][n] = *(const s16x8*)(Bs + (wc * 32 + n * 16 + lr) * 64 +
                                     ((ks * 4 + g) ^ sk) * 8);
    }
#pragma unroll
    for (int ks = 0; ks < 2; ++ks)
#pragma unroll
      for (int m = 0; m < 4; ++m)
#pragma unroll
        for (int n = 0; n < 2; ++n)
          acc[m][n] = __builtin_amdgcn_mfma_f32_16x16x32_bf16(
              af[ks][m], bfr[ks][n], acc[m][n], 0, 0, 0);
    __syncthreads();
  }

  // C/D layout: row = (l>>4)*4 + r, col = l&15  [HW-verified]
  if (c_f32) {
    float* C = (float*)Cp;
#pragma unroll
    for (int m = 0; m < 4; ++m)
#pragma unroll
      for (int n = 0; n < 2; ++n)
#pragma unroll
        for (int r = 0; r < 4; ++r)
          C[(size_t)(m0 + wr * 64 + m * 16 + g * 4 + r) * N +
            n0 + wc * 32 + n * 16 + lr] = acc[m][n][r];
  } else {
    unsigned short* C = (unsigned short*)Cp;
#pragma unroll
    for (int m = 0; m < 4; ++m)
#pragma unroll
      for (int n = 0; n < 2; ++n)
#pragma unroll
        for (int r = 0; r < 4; ++r)
          C[(size_t)(m0 + wr * 64 + m * 16 + g * 4 + r) * N +
            n0 + wc * 32 + n * 16 + lr] = f2bf(acc[m][n][r]);
  }
}

// ---------------- flash attention (R18 structure, exp2-domain softmax) ----------------
// 512 blocks; block n handles q-tile pair (31-ip, ip), ip = n>>5 -> uniform
// 33 tile-iters/block. 4 waves; wave w owns q rows [qt*64+16w, +16).
// KVBLK=64, double-buffered K/V. Lane (g,lr) holds S[q=qw+lr][kv=nf*16+g*4+r].
// Scores are in log2 units (LOG2E pre-folded into Q scale).
__global__ __launch_bounds__(256) void attn_fused(
    const unsigned short* __restrict__ QKV, unsigned short* __restrict__ Y) {
  __shared__ unsigned short Kt[2][64 * 64];   // [kv][d], swizzled
  __shared__ unsigned short Vt[2][64 * 64];   // [d][kv], swizzled
  __shared__ unsigned short Pb[4][16 * 64];   // per-wave P [q][kv], swizzled

  const int T = 2048, CS = 1536;
  int tid = threadIdx.x;
  int w = tid >> 6, l = tid & 63, g = l >> 4, lr = l & 15;
  int n = blockIdx.x;
  int ip = n >> 5;                     // pair index 0..15
  int bh = n & 31, b = bh >> 4, h = bh & 15, kvh = h >> 2;
  int sx = lr & 7;

  const unsigned short* Qp = QKV + (size_t)b * T * CS + h * 64;
  const unsigned short* Kp = QKV + (size_t)b * T * CS + 1024 + kvh * 64;
  const unsigned short* Vp = QKV + (size_t)b * T * CS + 1280 + kvh * 64;
  unsigned short* Pw = Pb[w];

  // V staging decode (R18): thread owns kv-pair (kvE, kvE+1) x d-chunk dcV;
  // b32-packed writes, store rule Vt[d][kv ^ ((d&7)*8)] preserved.
  int kvE = (tid & 31) * 2, dcV = ((tid >> 5) & 7) * 8;

  for (int pass = 0; pass < 2; ++pass) {
    int qt = pass == 0 ? (31 - ip) : ip;
    int qw = qt * 64 + w * 16;
    int q_mine = qw + lr;              // this lane's q-row

    s16x8 qf[2];
#pragma unroll
    for (int ks = 0; ks < 2; ++ks)
      qf[ks] = *(const s16x8*)(Qp + (size_t)q_mine * CS + ks * 32 + g * 8);

    f32x4 o[4] = {};
    float mrun = -1e30f, lrun = 0.f;
    int ntiles = qt + 1;

    // ---- prologue: stage tile 0 into buffer 0 ----
#pragma unroll
    for (int i = 0; i < 2; ++i) {
      int c = i * 256 + tid;
      int row = c >> 3, srcc = ((c & 7) ^ (row & 7)) * 8;
      async16(Kp + (size_t)row * CS + srcc, (char*)(&Kt[0][0]) + c * 16);
    }
    {
      s16x8 vE = *(const s16x8*)(Vp + (size_t)kvE * CS + dcV);
      s16x8 vO = *(const s16x8*)(Vp + (size_t)(kvE + 1) * CS + dcV);
#pragma unroll
      for (int j = 0; j < 8; ++j) {
        unsigned int pk = (unsigned int)(unsigned short)vE[j] |
                          ((unsigned int)(unsigned short)vO[j] << 16);
        *(unsigned int*)(&Vt[0][0] + (dcV + j) * 64 + (kvE ^ (j * 8))) = pk;
      }
    }
    __syncthreads();

    int cur = 0;
    for (int it = 0; it < ntiles; ++it) {
      int kv0 = it * 64;
      bool hasnext = (it + 1 < ntiles);

      // ---- T14 stage: issue next tile's K (async->LDS) and V (->regs) ----
      s16x8 vE, vO;
      if (hasnext) {
        int kvn = kv0 + 64;
#pragma unroll
        for (int i = 0; i < 2; ++i) {
          int c = i * 256 + tid;
          int row = c >> 3, srcc = ((c & 7) ^ (row & 7)) * 8;
          async16(Kp + (size_t)(kvn + row) * CS + srcc,
                  (char*)(&Kt[cur ^ 1][0]) + c * 16);
        }
        vE = *(const s16x8*)(Vp + (size_t)(kvn + kvE) * CS + dcV);
        vO = *(const s16x8*)(Vp + (size_t)(kvn + kvE + 1) * CS + dcV);
      }

      // ---- S^T = K Q^T: lane holds S[q_mine][kv = nf*16 + g*4 + r] ----
      const unsigned short* Kc = &Kt[cur][0];
      const unsigned short* Vc = &Vt[cur][0];
      f32x4 s[4];
      __builtin_amdgcn_s_setprio(1);
#pragma unroll
      for (int nf = 0; nf < 4; ++nf) {
        f32x4 z = {};
#pragma unroll
        for (int ks = 0; ks < 2; ++ks) {
          s16x8 kf = *(const s16x8*)(Kc + (nf * 16 + lr) * 64 +
                                     ((ks * 4 + g) ^ sx) * 8);
          z = __builtin_amdgcn_mfma_f32_16x16x32_bf16(kf, qf[ks], z, 0, 0, 0);
        }
        s[nf] = z;
      }
      __builtin_amdgcn_s_setprio(0);

      if (it == ntiles - 1) {   // diagonal tile: causal mask
#pragma unroll
        for (int nf = 0; nf < 4; ++nf)
#pragma unroll
          for (int r = 0; r < 4; ++r)
            if (kv0 + nf * 16 + g * 4 + r > q_mine) s[nf][r] = -1e30f;
      }

      // ---- softmax (exp2 domain): 16 in-lane values + 2 shuffles ----
      float mt = s[0][0];
#pragma unroll
      for (int nf = 0; nf < 4; ++nf)
#pragma unroll
        for (int r = 0; r < 4; ++r) mt = fmaxf(mt, s[nf][r]);
      mt = fmaxf(mt, __shfl_xor(mt, 16, 64));
      mt = fmaxf(mt, __shfl_xor(mt, 32, 64));

      if (__any(mt > mrun + 11.5416f)) {   // defer-max (8 nats in log2 units)
        float mnew = fmaxf(mrun, mt);
        float corr = exp2f(mrun - mnew);
        float psum = 0.f;
#pragma unroll
        for (int nf = 0; nf < 4; ++nf)
#pragma unroll
          for (int r = 0; r < 4; ++r) {
            float p = exp2f(s[nf][r] - mnew);
            s[nf][r] = p;
            psum += p;
          }
        psum += __shfl_xor(psum, 16, 64);
        psum += __shfl_xor(psum, 32, 64);
        lrun = lrun * corr + psum;
        mrun = mnew;
#pragma unroll
        for (int r = 0; r < 4; ++r) {
          float cr = __shfl(corr, g * 4 + r, 64);
#pragma unroll
          for (int d0 = 0; d0 < 4; ++d0) o[d0][r] *= cr;
        }
      } else {                         // fast path: no rescale
        float psum = 0.f;
#pragma unroll
        for (int nf = 0; nf < 4; ++nf)
#pragma unroll
          for (int r = 0; r < 4; ++r) {
            float p = exp2f(s[nf][r] - mrun);
            s[nf][r] = p;
            psum += p;
          }
        psum += __shfl_xor(psum, 16, 64);
        psum += __shfl_xor(psum, 32, 64);
        lrun += psum;
      }

      // ---- P -> LDS [q=lr][kv] via cvt_pk (b64 writes; RNE identical) ----
#pragma unroll
      for (int nf = 0; nf < 4; ++nf) {
        uint2 pv;
        pv.x = cvtpk(s[nf][0], s[nf][1]);
        pv.y = cvtpk(s[nf][2], s[nf][3]);
        *(uint2*)(Pw + lr * 64 + ((nf * 16 + g * 4) ^ (sx * 8))) = pv;
      }
      asm volatile("s_waitcnt lgkmcnt(0)" ::: "memory");
      __builtin_amdgcn_sched_barrier(0);   // rule #18

      s16x8 pf[2];
#pragma unroll
      for (int ks = 0; ks < 2; ++ks)
        pf[ks] = *(const s16x8*)(Pw + lr * 64 + ((ks * 4 + g) ^ sx) * 8);
      __builtin_amdgcn_s_setprio(1);
#pragma unroll
      for (int d0 = 0; d0 < 4; ++d0)
#pragma unroll
        for (int ks = 0; ks < 2; ++ks) {
          s16x8 vf = *(const s16x8*)(Vc + (d0 * 16 + lr) * 64 +
                                     ((ks * 4 + g) ^ sx) * 8);
          o[d0] = __builtin_amdgcn_mfma_f32_16x16x32_bf16(pf[ks], vf, o[d0], 0, 0, 0);
        }
      __builtin_amdgcn_s_setprio(0);

      // ---- write staged V regs -> back buffer (8x b32 packed) ----
      if (hasnext) {
        unsigned short* Vn = &Vt[cur ^ 1][0];
#pragma unroll
        for (int j = 0; j < 8; ++j) {
          unsigned int pk = (unsigned int)(unsigned short)vE[j] |
                            ((unsigned int)(unsigned short)vO[j] << 16);
          *(unsigned int*)(Vn + (dcV + j) * 64 + (kvE ^ (j * 8))) = pk;
        }
      }
      __syncthreads();   // drains vmcnt (K async) + lgkm (V writes)
      cur ^= 1;
    }

    // ---- epilogue: o rows are g*4+r; lrun lives at lane (*, lr=g*4+r) ----
#pragma unroll
    for (int r = 0; r < 4; ++r) {
      float lv = __shfl(lrun, g * 4 + r, 64);
      float inv = 1.f / lv;
      size_t rowoff = (size_t)(b * T + qw + g * 4 + r) * 1024 + h * 64;
#pragma unroll
      for (int d0 = 0; d0 < 4; ++d0)
        Y[rowoff + d0 * 16 + lr] = f2bf(o[d0][r] * inv);
    }
  }
}

// ---------------- launch ----------------

extern "C" void kernel_launch(void* const* d_in, const int* in_sizes, int n_in,
                              void* d_out, int out_size, void* d_ws, size_t ws_size,
                              hipStream_t stream) {
  const float* x    = (const float*)d_in[0];
  const float* cosb = (const float*)d_in[1];
  const float* sinb = (const float*)d_in[2];
  const float* Wq   = (const float*)d_in[3];
  const float* Wk   = (const float*)d_in[4];
  const float* Wv   = (const float*)d_in[5];
  const float* Wo   = (const float*)d_in[6];
  float* out = (float*)d_out;

  // Buffer map:
  //   d_out (16 MB): QKVb [4096][1536] bf16 = 12 MB  (dead at final gemm)
  //   d_ws: xb 0..8M | Wqkvt 8..11M | Wot 11..13M ; Yb aliases xb after attn
  char* ob = (char*)d_out;
  char* ws = (char*)d_ws;
  const size_t MB = 1024 * 1024;
  unsigned short* QKVb  = (unsigned short*)(ob);
  unsigned short* xb    = (unsigned short*)(ws);
  unsigned short* Wqkvt = (unsigned short*)(ws + 8 * MB);
  unsigned short* Wot   = (unsigned short*)(ws + 11 * MB);
  unsigned short* Yb    = xb;   // x-content dead after QKV gemm

  conv_f32_to_bf16<<<4096, 256, 0, stream>>>(x, xb, 4096 * 1024);
  // pack W_qkv^T rows: [0,1024) = Wq, [1024,1280) = Wk, [1280,1536) = Wv
  transpose_conv4<<<dim3(32, 32, 4), dim3(32, 8), 0, stream>>>(
      Wq, Wk, Wv, Wo,
      Wqkvt, Wqkvt + (size_t)1024 * 1024, Wqkvt + (size_t)1280 * 1024, Wot);

  // fused QKV projection: [4096][1536] bf16 (768 blocks, XCD-chunked)
  gemm_bt<<<dim3(768), 256, 0, stream>>>(xb, Wqkvt, QKVb, 4096, 1536, 1024, 0);

  // RoPE on Q (x0.125*log2e) + K in one pass
  rope_qk<<<10240, 256, 0, stream>>>(QKVb, cosb, sinb);

  // attention -> Yb bf16 [B*T][1024]
  attn_fused<<<dim3(512), 256, 0, stream>>>(QKVb, Yb);

  // output projection (fp32, overwrites d_out; 512 blocks, XCD-chunked)
  gemm_bt<<<dim3(512), 256, 0, stream>>>(Yb, Wot, out, 4096, 1024, 1024, 1);
}